// Round 17
// baseline (162.522 us; speedup 1.0000x reference)
//
#include <hip/hip_runtime.h>
#include <math.h>

#define N_NODES 50000
#define N_HEDGE 5000
#define N_EDGES 400000
#define NB 2
#define NC 64
#define NEG 0.2f
#define NROWS (N_NODES * NB)   // 100000
#define MAXDEG 64              // padded-CSR stride; true max degree ~25 (15σ margin)

#define GEMM_BLOCKS ((NROWS + 127) / 128)      // 782 (128 rows per block)
#define GEMM_THREADS (GEMM_BLOCKS * 256)       // 200192 (each covers 2 edges)
#define SCAT_BLOCKS ((N_EDGES + 255) / 256)    // 1563
#define HEDGE_BLOCKS ((N_HEDGE + 3) / 4)       // 1250
#define PITCH 66               // LDS row pitch: 8-row stride = 528 words ≡ 16 mod 32
                               // (same conflict-free bank pattern as the measured-0 68-pitch)

__device__ __forceinline__ unsigned short f2bf(float f) {
    unsigned int u = __float_as_uint(f);
    unsigned int r = (u + 0x7FFFu + ((u >> 16) & 1u)) >> 16;   // RNE
    return (unsigned short)r;
}

__device__ __forceinline__ float lrelu_exp(float r) {
    r = (r >= 0.f) ? r : NEG * r;
    r = fmaxf(r, -80.f);          // denom stays > 0 even pathologically
    return __expf(r);
}

// ---------------- GEMM: xw[row][c] bf16, row = n*2+b; epilogue p1/p2
// R17 restructure (gemm was 47us @ 17% VALU / 11% HBM — LDS-traffic +
// staging-serialization + exposed atomic tail):
//  * 128 rows/block, 8x4 per thread: 12 LDS reads per 128 FMA (was 8/64)
//  * register-staged global loads (one latency epoch, then LDS writes)
//  * count-atomics issued right after the staging barrier — return latency
//    hides under the k4 compute; rank stored at kernel end
__global__ __launch_bounds__(256, 3) void gemm_kernel(const float* __restrict__ x,
                                                      const float* __restrict__ W,
                                                      const float* __restrict__ att,
                                                      const int* __restrict__ node_idx,
                                                      const int* __restrict__ hedge_idx,
                                                      unsigned short* __restrict__ xwb,
                                                      float* __restrict__ p1,
                                                      float* __restrict__ p2,
                                                      int* __restrict__ cnt,
                                                      int* __restrict__ rank,
                                                      int* __restrict__ estart)
{
    __shared__ float xs[128 * PITCH];   // 33792 B
    __shared__ float Ws[64 * PITCH];    // 16896 B
    int t = threadIdx.x;
    int R = blockIdx.x * 128;
    int tq = t >> 4, tc = t & 15;       // tq: load-row group / compute row group

    // ---- register-stage all global loads (independent, single latency epoch)
    float4 w0 = ((const float4*)W)[t];
    float4 w1 = ((const float4*)W)[t + 256];
    float4 w2 = ((const float4*)W)[t + 512];
    float4 w3 = ((const float4*)W)[t + 768];
    float4 x0, x1, x2, x3, x4, x5, x6, x7;
    {
        float4 z = make_float4(0.f, 0.f, 0.f, 0.f);
        x0 = z; x1 = z; x2 = z; x3 = z; x4 = z; x5 = z; x6 = z; x7 = z;
#define LOADX(idx, dst) { int g = R + tq + 16 * idx;                                   \
        if (g < NROWS) { int n = g >> 1, b = g & 1;                                    \
            dst = ((const float4*)(x + ((size_t)b * N_NODES + n) * NC))[tc]; } }
        LOADX(0, x0) LOADX(1, x1) LOADX(2, x2) LOADX(3, x3)
        LOADX(4, x4) LOADX(5, x5) LOADX(6, x6) LOADX(7, x7)
#undef LOADX
    }
    // ---- LDS writes
    *(float4*)&Ws[(tq +  0) * PITCH + tc * 4] = w0;
    *(float4*)&Ws[(tq + 16) * PITCH + tc * 4] = w1;
    *(float4*)&Ws[(tq + 32) * PITCH + tc * 4] = w2;
    *(float4*)&Ws[(tq + 48) * PITCH + tc * 4] = w3;
    *(float4*)&xs[(tq +   0) * PITCH + tc * 4] = x0;
    *(float4*)&xs[(tq +  16) * PITCH + tc * 4] = x1;
    *(float4*)&xs[(tq +  32) * PITCH + tc * 4] = x2;
    *(float4*)&xs[(tq +  48) * PITCH + tc * 4] = x3;
    *(float4*)&xs[(tq +  64) * PITCH + tc * 4] = x4;
    *(float4*)&xs[(tq +  80) * PITCH + tc * 4] = x5;
    *(float4*)&xs[(tq +  96) * PITCH + tc * 4] = x6;
    *(float4*)&xs[(tq + 112) * PITCH + tc * 4] = x7;
    __syncthreads();

    // ---- issue count-atomics NOW: return latency hides under the k4 loop
    int gid = blockIdx.x * 256 + t;           // always < N_EDGES (200192 - 1 max)
    int gid2 = gid + GEMM_THREADS;
    bool v2 = gid2 < N_EDGES;
    int rk0 = atomicAdd(&cnt[node_idx[gid]], 1);
    int rk1 = 0;
    if (v2) rk1 = atomicAdd(&cnt[node_idx[gid2]], 1);

    // ---- 8x4 per-thread GEMM: rows tq*8..tq*8+7, cols tc*4..tc*4+3
    float acc[8][4];
#pragma unroll
    for (int i = 0; i < 8; i++)
#pragma unroll
        for (int j = 0; j < 4; j++) acc[i][j] = 0.f;

#pragma unroll 4
    for (int k4 = 0; k4 < 16; k4++) {
        float4 wv[4];
#pragma unroll
        for (int kk = 0; kk < 4; kk++)
            wv[kk] = *(const float4*)&Ws[(k4 * 4 + kk) * PITCH + tc * 4];
        float4 xv[8];
#pragma unroll
        for (int i = 0; i < 8; i++)
            xv[i] = *(const float4*)&xs[(tq * 8 + i) * PITCH + k4 * 4];
#pragma unroll
        for (int i = 0; i < 8; i++) {
            acc[i][0] = fmaf(xv[i].x, wv[0].x, acc[i][0]);
            acc[i][1] = fmaf(xv[i].x, wv[0].y, acc[i][1]);
            acc[i][2] = fmaf(xv[i].x, wv[0].z, acc[i][2]);
            acc[i][3] = fmaf(xv[i].x, wv[0].w, acc[i][3]);
            acc[i][0] = fmaf(xv[i].y, wv[1].x, acc[i][0]);
            acc[i][1] = fmaf(xv[i].y, wv[1].y, acc[i][1]);
            acc[i][2] = fmaf(xv[i].y, wv[1].z, acc[i][2]);
            acc[i][3] = fmaf(xv[i].y, wv[1].w, acc[i][3]);
            acc[i][0] = fmaf(xv[i].z, wv[2].x, acc[i][0]);
            acc[i][1] = fmaf(xv[i].z, wv[2].y, acc[i][1]);
            acc[i][2] = fmaf(xv[i].z, wv[2].z, acc[i][2]);
            acc[i][3] = fmaf(xv[i].z, wv[2].w, acc[i][3]);
            acc[i][0] = fmaf(xv[i].w, wv[3].x, acc[i][0]);
            acc[i][1] = fmaf(xv[i].w, wv[3].y, acc[i][1]);
            acc[i][2] = fmaf(xv[i].w, wv[3].z, acc[i][2]);
            acc[i][3] = fmaf(xv[i].w, wv[3].w, acc[i][3]);
        }
    }

    float a1x = att[tc * 4], a1y = att[tc * 4 + 1], a1z = att[tc * 4 + 2], a1w = att[tc * 4 + 3];
    float a2x = att[64 + tc * 4], a2y = att[64 + tc * 4 + 1], a2z = att[64 + tc * 4 + 2], a2w = att[64 + tc * 4 + 3];
#pragma unroll
    for (int i = 0; i < 8; i++) {
        int g = R + tq * 8 + i;
        if (g < NROWS) {
            ushort4 bv;
            bv.x = f2bf(acc[i][0]); bv.y = f2bf(acc[i][1]);
            bv.z = f2bf(acc[i][2]); bv.w = f2bf(acc[i][3]);
            ((ushort4*)(xwb + (size_t)g * 64))[tc] = bv;
        }
        float v1 = acc[i][0] * a1x + acc[i][1] * a1y + acc[i][2] * a1z + acc[i][3] * a1w;
        float v2r = acc[i][0] * a2x + acc[i][1] * a2y + acc[i][2] * a2z + acc[i][3] * a2w;
#pragma unroll
        for (int off = 8; off >= 1; off >>= 1) {
            v1 += __shfl_xor(v1, off, 64);
            v2r += __shfl_xor(v2r, off, 64);
        }
        if (tc == 0 && g < NROWS) { p1[g] = v1; p2[g] = v2r; }
    }

    // ---- drain the count work (atomic returns long since arrived)
    rank[gid] = rk0;
    if (v2) rank[gid2] = rk1;
    if (gid <= N_HEDGE) {
        int lo = 0, hi = N_EDGES;
        while (lo < hi) {
            int mid = (lo + hi) >> 1;
            if (hedge_idx[mid] < gid) lo = mid + 1; else hi = mid;
        }
        estart[gid] = lo;
    }
}

// ---------------- fused: padded-CSR scatter + per-hyperedge p2 sums.
__global__ __launch_bounds__(256) void sh_kernel(const int* __restrict__ node_idx,
                                                 const int* __restrict__ hedge_idx,
                                                 const int* __restrict__ rank,
                                                 int* __restrict__ hperm,
                                                 const float* __restrict__ p2,
                                                 const int* __restrict__ estart,
                                                 float* __restrict__ s2)
{
    if (blockIdx.x < SCAT_BLOCKS) {
        int e = blockIdx.x * 256 + threadIdx.x;
        if (e >= N_EDGES) return;
        int n = node_idx[e];
        int r = rank[e];
        if (r < MAXDEG) hperm[(n << 6) + r] = hedge_idx[e];
    } else {
        int wv = (blockIdx.x - SCAT_BLOCKS) * 4 + (threadIdx.x >> 6);
        if (wv >= N_HEDGE) return;
        int lane = threadIdx.x & 63;
        int s = estart[wv], e1 = estart[wv + 1];
        float a0 = 0.f, a1 = 0.f;
        for (int e = s + lane; e < e1; e += 128) {
            int eB = e + 64; bool vB = eB < e1;
            int nA = node_idx[e];
            int nB = node_idx[vB ? eB : s];
            float2 pA = ((const float2*)p2)[nA];
            float2 pB = ((const float2*)p2)[nB];
            a0 += pA.x + (vB ? pB.x : 0.f);
            a1 += pA.y + (vB ? pB.y : 0.f);
        }
#pragma unroll
        for (int off = 32; off >= 1; off >>= 1) {
            a0 += __shfl_xor(a0, off, 64);
            a1 += __shfl_xor(a1, off, 64);
        }
        if (lane == 0) { s2[wv * 2] = a0; s2[wv * 2 + 1] = a1; }
    }
}

// ---------------- den: 8 lanes per node (sub-wave parallel), shfl reduce.
// Padded CSR: segment = [n*64, n*64 + cnt[n]). Feeds m_kernel only.
__global__ __launch_bounds__(256) void den_kernel(const int* __restrict__ cnt,
                                                  const int* __restrict__ hperm,
                                                  const float* __restrict__ p1,
                                                  const float* __restrict__ s2,
                                                  float* __restrict__ den)
{
    int t = threadIdx.x;
    int n = blockIdx.x * 32 + (t >> 3);
    if (n >= N_NODES) return;
    int sub = t & 7;
    int s = n << 6;
    int d = cnt[n]; if (d > MAXDEG) d = MAXDEG;
    int e1 = s + d;
    float2 pn = ((const float2*)p1)[n];
    const float2* s2v = (const float2*)s2;
    float a0 = 0.f, a1 = 0.f;
    for (int j = s + sub; j < e1; j += 8) {
        float2 v = s2v[hperm[j]];
        a0 += lrelu_exp(pn.x + v.x);
        a1 += lrelu_exp(pn.y + v.y);
    }
#pragma unroll
    for (int off = 1; off < 8; off <<= 1) {   // reduce within the 8-lane group
        a0 += __shfl_xor(a0, off, 64);
        a1 += __shfl_xor(a1, off, 64);
    }
    if (sub == 0) ((float2*)den)[n] = make_float2(a0, a1);
}

// ---------------- pass 1: m[h][k] = (1/deg_h) * sum_{e in h} (ev_e/den[n_e]) * xw[n_e][k]
// R15 economy layout: 16 lanes per edge-row (16B uint4/lane), 4 edge-slot
// groups per wave, slots A/B/C/D at eb+g, +16, +32, +48 (stride 64).
__global__ __launch_bounds__(256) void m_kernel(const unsigned short* __restrict__ xwb,
                                                const int* __restrict__ node_idx,
                                                const int* __restrict__ estart,
                                                const float* __restrict__ p1,
                                                const float* __restrict__ s2,
                                                const float* __restrict__ den,
                                                float* __restrict__ m)
{
    __shared__ float red[3][128];
    int h = blockIdx.x;
    int t = threadIdx.x;
    int w = t >> 6, l = t & 63;
    int g = l >> 4;                 // edge slot group within wave
    int i = l & 15;                 // sublane: owns elements 8i..8i+7 of the 128-row
    int b = i >> 3;                 // batch (uniform per lane)
    int s = estart[h], e1 = estart[h + 1];
    float2 s2h = ((const float2*)s2)[h];  // block-uniform
    float sb = b ? s2h.y : s2h.x;

    float c0 = 0.f, c1 = 0.f, c2 = 0.f, c3 = 0.f;
    float c4 = 0.f, c5 = 0.f, c6 = 0.f, c7 = 0.f;

    for (int eb = s + 4 * w; eb < e1; eb += 64) {      // wave-uniform loop bound
        int eA = eb + g;      bool vA = eA < e1;
        int eB = eb + 16 + g; bool vB = eB < e1;
        int eC = eb + 32 + g; bool vC = eC < e1;
        int eD = eb + 48 + g; bool vD = eD < e1;
        int nA = node_idx[vA ? eA : s];
        int nB = node_idx[vB ? eB : s];
        int nC = node_idx[vC ? eC : s];
        int nD = node_idx[vD ? eD : s];
        float pA = p1[2 * nA + b], pB = p1[2 * nB + b];
        float pC = p1[2 * nC + b], pD = p1[2 * nD + b];
        float dA = den[2 * nA + b], dB = den[2 * nB + b];
        float dC = den[2 * nC + b], dD = den[2 * nD + b];
        uint4 qA = *(const uint4*)&xwb[(size_t)nA * 128 + 8 * i];
        uint4 qB = *(const uint4*)&xwb[(size_t)nB * 128 + 8 * i];
        uint4 qC = *(const uint4*)&xwb[(size_t)nC * 128 + 8 * i];
        uint4 qD = *(const uint4*)&xwb[(size_t)nD * 128 + 8 * i];

        float aA = lrelu_exp(pA + sb) * __builtin_amdgcn_rcpf(dA); aA = vA ? aA : 0.f;
        float aB = lrelu_exp(pB + sb) * __builtin_amdgcn_rcpf(dB); aB = vB ? aB : 0.f;
        float aC = lrelu_exp(pC + sb) * __builtin_amdgcn_rcpf(dC); aC = vC ? aC : 0.f;
        float aD = lrelu_exp(pD + sb) * __builtin_amdgcn_rcpf(dD); aD = vD ? aD : 0.f;

        c0 = fmaf(aA, __uint_as_float(qA.x << 16), c0);
        c1 = fmaf(aA, __uint_as_float(qA.x & 0xffff0000u), c1);
        c2 = fmaf(aA, __uint_as_float(qA.y << 16), c2);
        c3 = fmaf(aA, __uint_as_float(qA.y & 0xffff0000u), c3);
        c4 = fmaf(aA, __uint_as_float(qA.z << 16), c4);
        c5 = fmaf(aA, __uint_as_float(qA.z & 0xffff0000u), c5);
        c6 = fmaf(aA, __uint_as_float(qA.w << 16), c6);
        c7 = fmaf(aA, __uint_as_float(qA.w & 0xffff0000u), c7);
        c0 = fmaf(aB, __uint_as_float(qB.x << 16), c0);
        c1 = fmaf(aB, __uint_as_float(qB.x & 0xffff0000u), c1);
        c2 = fmaf(aB, __uint_as_float(qB.y << 16), c2);
        c3 = fmaf(aB, __uint_as_float(qB.y & 0xffff0000u), c3);
        c4 = fmaf(aB, __uint_as_float(qB.z << 16), c4);
        c5 = fmaf(aB, __uint_as_float(qB.z & 0xffff0000u), c5);
        c6 = fmaf(aB, __uint_as_float(qB.w << 16), c6);
        c7 = fmaf(aB, __uint_as_float(qB.w & 0xffff0000u), c7);
        c0 = fmaf(aC, __uint_as_float(qC.x << 16), c0);
        c1 = fmaf(aC, __uint_as_float(qC.x & 0xffff0000u), c1);
        c2 = fmaf(aC, __uint_as_float(qC.y << 16), c2);
        c3 = fmaf(aC, __uint_as_float(qC.y & 0xffff0000u), c3);
        c4 = fmaf(aC, __uint_as_float(qC.z << 16), c4);
        c5 = fmaf(aC, __uint_as_float(qC.z & 0xffff0000u), c5);
        c6 = fmaf(aC, __uint_as_float(qC.w << 16), c6);
        c7 = fmaf(aC, __uint_as_float(qC.w & 0xffff0000u), c7);
        c0 = fmaf(aD, __uint_as_float(qD.x << 16), c0);
        c1 = fmaf(aD, __uint_as_float(qD.x & 0xffff0000u), c1);
        c2 = fmaf(aD, __uint_as_float(qD.y << 16), c2);
        c3 = fmaf(aD, __uint_as_float(qD.y & 0xffff0000u), c3);
        c4 = fmaf(aD, __uint_as_float(qD.z << 16), c4);
        c5 = fmaf(aD, __uint_as_float(qD.z & 0xffff0000u), c5);
        c6 = fmaf(aD, __uint_as_float(qD.w << 16), c6);
        c7 = fmaf(aD, __uint_as_float(qD.w & 0xffff0000u), c7);
    }

    // reduce across the 4 edge-slot groups (lanes i, i+16, i+32, i+48)
#pragma unroll
    for (int off = 16; off <= 32; off <<= 1) {
        c0 += __shfl_xor(c0, off, 64);
        c1 += __shfl_xor(c1, off, 64);
        c2 += __shfl_xor(c2, off, 64);
        c3 += __shfl_xor(c3, off, 64);
        c4 += __shfl_xor(c4, off, 64);
        c5 += __shfl_xor(c5, off, 64);
        c6 += __shfl_xor(c6, off, 64);
        c7 += __shfl_xor(c7, off, 64);
    }
    // cross-wave reduce via LDS (waves 1..3 -> wave 0), lanes l<16 carry data
    if (w && l < 16) {
        float* r = &red[w - 1][8 * l];
        r[0] = c0; r[1] = c1; r[2] = c2; r[3] = c3;
        r[4] = c4; r[5] = c5; r[6] = c6; r[7] = c7;
    }
    __syncthreads();
    if (w == 0 && l < 16) {
#pragma unroll
        for (int k = 0; k < 3; k++) {
            const float* r = &red[k][8 * l];
            c0 += r[0]; c1 += r[1]; c2 += r[2]; c3 += r[3];
            c4 += r[4]; c5 += r[5]; c6 += r[6]; c7 += r[7];
        }
        int d = e1 - s;
        float binv = (d > 0) ? 1.0f / (float)d : 0.0f;
        float* dst = m + (size_t)h * 128 + 8 * l;
        *(float4*)dst = make_float4(binv * c0, binv * c1, binv * c2, binv * c3);
        *(float4*)(dst + 4) = make_float4(binv * c4, binv * c5, binv * c6, binv * c7);
    }
}

// ---------------- pass 2: out[b][n][c] = (deg/den[n]) * sum_j ev_j * m[h_j][k]
// R14 economy layout + self-computed den; padded CSR segment [n*64, n*64+d).
__global__ __launch_bounds__(256) void out_kernel(const float* __restrict__ m,
                                                  const int* __restrict__ hperm,
                                                  const float* __restrict__ p1,
                                                  const float* __restrict__ s2,
                                                  const int* __restrict__ cnt,
                                                  float* __restrict__ out)
{
    int n = blockIdx.x * 4 + (threadIdx.x >> 6);
    if (n >= N_NODES) return;
    int l = threadIdx.x & 63;
    int g = l >> 5;                 // edge slot (0,1)
    int i = l & 31;                 // owns m-row elements 4i..4i+3
    int b = i >> 4;                 // batch: elements >=64 are batch 1
    int d = cnt[n]; if (d > MAXDEG) d = MAXDEG;
    int s = n << 6;
    int e1 = s + d;
    float pnb = p1[2 * n + b];
    const float2* s2v = (const float2*)s2;
    float c0 = 0.f, c1 = 0.f, c2 = 0.f, c3 = 0.f, sden = 0.f;

    for (int jb = s; jb < e1; jb += 8) {       // 8 edges/iter: 2 slots x 4 unroll
        int jA = jb + g;     bool vA = jA < e1;
        int jB = jb + 2 + g; bool vB = jB < e1;
        int jC = jb + 4 + g; bool vC = jC < e1;
        int jD = jb + 6 + g; bool vD = jD < e1;
        int hA = hperm[vA ? jA : s];
        int hB = hperm[vB ? jB : s];
        int hC = hperm[vC ? jC : s];
        int hD = hperm[vD ? jD : s];
        float2 wA = s2v[hA], wB = s2v[hB], wC = s2v[hC], wD = s2v[hD];
        float4 mA = *(const float4*)(m + (size_t)hA * 128 + 4 * i);
        float4 mB = *(const float4*)(m + (size_t)hB * 128 + 4 * i);
        float4 mC = *(const float4*)(m + (size_t)hC * 128 + 4 * i);
        float4 mD = *(const float4*)(m + (size_t)hD * 128 + 4 * i);
        float aA = lrelu_exp(pnb + (b ? wA.y : wA.x)); aA = vA ? aA : 0.f;
        float aB = lrelu_exp(pnb + (b ? wB.y : wB.x)); aB = vB ? aB : 0.f;
        float aC = lrelu_exp(pnb + (b ? wC.y : wC.x)); aC = vC ? aC : 0.f;
        float aD = lrelu_exp(pnb + (b ? wD.y : wD.x)); aD = vD ? aD : 0.f;
        sden += ((aA + aB) + aC) + aD;
        c0 = fmaf(aA, mA.x, c0); c1 = fmaf(aA, mA.y, c1);
        c2 = fmaf(aA, mA.z, c2); c3 = fmaf(aA, mA.w, c3);
        c0 = fmaf(aB, mB.x, c0); c1 = fmaf(aB, mB.y, c1);
        c2 = fmaf(aB, mB.z, c2); c3 = fmaf(aB, mB.w, c3);
        c0 = fmaf(aC, mC.x, c0); c1 = fmaf(aC, mC.y, c1);
        c2 = fmaf(aC, mC.z, c2); c3 = fmaf(aC, mC.w, c3);
        c0 = fmaf(aD, mD.x, c0); c1 = fmaf(aD, mD.y, c1);
        c2 = fmaf(aD, mD.z, c2); c3 = fmaf(aD, mD.w, c3);
    }
    // merge the two edge slots (lane i of slot 0 with lane i of slot 1)
    c0 += __shfl_xor(c0, 32, 64);
    c1 += __shfl_xor(c1, 32, 64);
    c2 += __shfl_xor(c2, 32, 64);
    c3 += __shfl_xor(c3, 32, 64);
    sden += __shfl_xor(sden, 32, 64);
    if (l < 32) {
        // deg * (1/den); zero-degree nodes write exact 0 (c=0, scale=0)
        float scale = (d > 0) ? (float)d * __builtin_amdgcn_rcpf(sden) : 0.f;
        int c = (4 * i) & 63;
        float* dst = out + (size_t)b * N_NODES * 64 + (size_t)n * 64 + c;
        __builtin_nontemporal_store(scale * c0, &dst[0]);
        __builtin_nontemporal_store(scale * c1, &dst[1]);
        __builtin_nontemporal_store(scale * c2, &dst[2]);
        __builtin_nontemporal_store(scale * c3, &dst[3]);
    }
}

extern "C" void kernel_launch(void* const* d_in, const int* in_sizes, int n_in,
                              void* d_out, int out_size, void* d_ws, size_t ws_size,
                              hipStream_t stream)
{
    const float* x      = (const float*)d_in[0];
    const float* W      = (const float*)d_in[1];
    const float* att    = (const float*)d_in[2];
    const int* node_idx = (const int*)d_in[3];
    const int* hedge_idx= (const int*)d_in[4];
    float* out = (float*)d_out;

    // workspace layout — ~31MB total (padded hperm 12.8MB)
    unsigned short* xwb = (unsigned short*)d_ws;        // 6,400,000 ushort (12.8MB)
    float* p1     = (float*)(xwb + (size_t)NROWS * NC); // 100,000
    float* p2     = p1 + NROWS;                         // 100,000
    float* s2     = p2 + NROWS;                         // 10,000
    float* m      = s2 + 10000;                         // 640,000
    float* den    = m + (size_t)N_HEDGE * NB * NC;      // 100,000
    int* estart  = (int*)(den + NROWS);                 // 5,008 (padded)
    int* cnt     = estart + 5008;                       // 50,000 (memset region)
    int* rank    = cnt + N_NODES;                       // 400,000
    int* hperm   = rank + N_EDGES;                      // 3,200,000 (padded CSR)

    hipMemsetAsync(cnt, 0, (size_t)N_NODES * sizeof(int), stream);

    gemm_kernel<<<GEMM_BLOCKS, 256, 0, stream>>>(x, W, att, node_idx, hedge_idx,
                                                 xwb, p1, p2, cnt, rank, estart);
    sh_kernel<<<SCAT_BLOCKS + HEDGE_BLOCKS, 256, 0, stream>>>(node_idx, hedge_idx, rank,
                                                              hperm, p2, estart, s2);
    den_kernel<<<(N_NODES + 31) / 32, 256, 0, stream>>>(cnt, hperm, p1, s2, den);
    m_kernel<<<N_HEDGE, 256, 0, stream>>>(xwb, node_idx, estart, p1, s2, den, m);
    out_kernel<<<(N_NODES + 3) / 4, 256, 0, stream>>>(m, hperm, p1, s2, cnt, out);
}